// Round 2
// baseline (115.160 us; speedup 1.0000x reference)
//
#include <hip/hip_runtime.h>

// Problem constants (fixed by the reference)
#define BB 2048
#define CC 50
#define DD 512
#define HH 51   // D // 10

__global__ __launch_bounds__(512) void ConstraintFuser_kernel(
    const float* __restrict__ q,      // [B, D]
    const int*   __restrict__ heads,  // [B, C]
    const int*   __restrict__ tails,  // [B, C]
    const int*   __restrict__ rels,   // [B, C]
    const float* __restrict__ ent,    // [NE+1, D]
    const float* __restrict__ rel,    // [NR+1, D]
    const float* __restrict__ w1,     // [D, H]
    const float* __restrict__ b1,     // [H]
    const float* __restrict__ w2,     // [H, D]
    const float* __restrict__ b2,     // [D]
    float* __restrict__ out)          // [B, D]
{
    const int b    = blockIdx.x;
    const int tid  = threadIdx.x;
    const int wave = tid >> 6;
    const int lane = tid & 63;

    __shared__ float  s_q[DD];          // 2 KB
    __shared__ float  s_score[CC];
    __shared__ float  s_pool[DD];       // 2 KB
    __shared__ float4 s_red4[4][128];   // 8 KB (reused: pooled reduce, out reduce)
    __shared__ float  s_wred[8][HH];    // phase-3 partials
    __shared__ float  s_mid[HH];
    __shared__ int    s_h[CC], s_t[CC], s_r[CC];

    // ---- stage indices + query row ----
    if (tid < CC) {
        s_h[tid] = heads[b * CC + tid];
        s_t[tid] = tails[b * CC + tid];
        s_r[tid] = rels [b * CC + tid];
    }
    if (tid < 128) {
        ((float4*)s_q)[tid] = ((const float4*)(q + (size_t)b * DD))[tid];
    }
    __syncthreads();

    // ---- phase 0: register-stage (tail + rel) rows — independent of scores,
    // so these 26 float4 loads/thread go in flight BEFORE + DURING phase 1 ----
    const int cg = tid >> 7;    // 0..3  c-group
    const int dv = tid & 127;   // float4 index within row
    float4 tr[13];
    #pragma unroll
    for (int i = 0; i < 13; ++i) {
        const int c = cg + i * 4;
        if (c < CC) {
            const float4 t4 = ((const float4*)(ent + (size_t)s_t[c] * DD))[dv];
            const float4 r4 = ((const float4*)(rel + (size_t)s_r[c] * DD))[dv];
            tr[i].x = t4.x + r4.x;
            tr[i].y = t4.y + r4.y;
            tr[i].z = t4.z + r4.z;
            tr[i].w = t4.w + r4.w;
        }
    }

    // each lane's fixed 8-float slot of q (for phase 1)
    const float4 q0 = ((const float4*)s_q)[lane * 2];
    const float4 q1 = ((const float4*)s_q)[lane * 2 + 1];

    // ---- phase 1: head_score[c] = dot(q, ent[heads[c]]) ----
    for (int c = wave; c < CC; c += 8) {
        const float4* hrow = (const float4*)(ent + (size_t)s_h[c] * DD);
        const float4 h0 = hrow[lane * 2];
        const float4 h1 = hrow[lane * 2 + 1];
        float p = q0.x * h0.x + q0.y * h0.y + q0.z * h0.z + q0.w * h0.w
                + q1.x * h1.x + q1.y * h1.y + q1.z * h1.z + q1.w * h1.w;
        #pragma unroll
        for (int off = 32; off > 0; off >>= 1) p += __shfl_xor(p, off, 64);
        if (lane == 0) s_score[c] = p;
    }
    __syncthreads();

    // ---- phase 2: pooled[d] = sum_c score[c] * tr[c][d] (regs already loaded) ----
    float4 acc = make_float4(0.f, 0.f, 0.f, 0.f);
    #pragma unroll
    for (int i = 0; i < 13; ++i) {
        const int c = cg + i * 4;
        if (c < CC) {
            const float sc = s_score[c];
            acc.x += sc * tr[i].x;
            acc.y += sc * tr[i].y;
            acc.z += sc * tr[i].z;
            acc.w += sc * tr[i].w;
        }
    }
    s_red4[cg][dv] = acc;
    __syncthreads();
    if (tid < 128) {
        const float4 a0 = s_red4[0][tid];
        const float4 a1 = s_red4[1][tid];
        const float4 a2 = s_red4[2][tid];
        const float4 a3 = s_red4[3][tid];
        float4 p;
        p.x = a0.x + a1.x + a2.x + a3.x;
        p.y = a0.y + a1.y + a2.y + a3.y;
        p.z = a0.z + a1.z + a2.z + a3.z;
        p.w = a0.w + a1.w + a2.w + a3.w;
        ((float4*)s_pool)[tid] = p;
    }
    __syncthreads();

    // ---- phase 3: mid = relu(pooled @ w1 + b1); wave w owns d in [64w, 64w+64) ----
    if (lane < HH) {
        const int d0 = wave * 64;
        float partial = 0.f;
        #pragma unroll 8
        for (int j = 0; j < 64; ++j) {
            partial += s_pool[d0 + j] * w1[(size_t)(d0 + j) * HH + lane];
        }
        s_wred[wave][lane] = partial;
    }
    __syncthreads();
    if (tid < HH) {
        float m = b1[tid];
        #pragma unroll
        for (int w = 0; w < 8; ++w) m += s_wred[w][tid];
        s_mid[tid] = m > 0.f ? m : 0.f;
    }
    __syncthreads();

    // ---- phase 4: out = mid @ w2 + b2 + q ----
    float4 acc2 = make_float4(0.f, 0.f, 0.f, 0.f);
    #pragma unroll
    for (int i = 0; i < 13; ++i) {
        const int h = cg + i * 4;
        if (h < HH) {
            const float  m  = s_mid[h];
            const float4 wv = ((const float4*)(w2 + (size_t)h * DD))[dv];
            acc2.x += m * wv.x;
            acc2.y += m * wv.y;
            acc2.z += m * wv.z;
            acc2.w += m * wv.w;
        }
    }
    s_red4[cg][dv] = acc2;
    __syncthreads();
    if (tid < 128) {
        const float4 a0 = s_red4[0][tid];
        const float4 a1 = s_red4[1][tid];
        const float4 a2 = s_red4[2][tid];
        const float4 a3 = s_red4[3][tid];
        const float4 bb = ((const float4*)b2)[tid];
        const float4 qq = ((const float4*)s_q)[tid];
        float4 o;
        o.x = a0.x + a1.x + a2.x + a3.x + bb.x + qq.x;
        o.y = a0.y + a1.y + a2.y + a3.y + bb.y + qq.y;
        o.z = a0.z + a1.z + a2.z + a3.z + bb.z + qq.z;
        o.w = a0.w + a1.w + a2.w + a3.w + bb.w + qq.w;
        ((float4*)(out + (size_t)b * DD))[tid] = o;
    }
}

extern "C" void kernel_launch(void* const* d_in, const int* in_sizes, int n_in,
                              void* d_out, int out_size, void* d_ws, size_t ws_size,
                              hipStream_t stream) {
    const float* q     = (const float*)d_in[0];
    const int*   heads = (const int*)  d_in[1];
    const int*   tails = (const int*)  d_in[2];
    const int*   rels  = (const int*)  d_in[3];
    const float* ent   = (const float*)d_in[4];
    const float* rel   = (const float*)d_in[5];
    const float* w1    = (const float*)d_in[6];
    const float* b1    = (const float*)d_in[7];
    const float* w2    = (const float*)d_in[8];
    const float* b2    = (const float*)d_in[9];
    float* out = (float*)d_out;

    ConstraintFuser_kernel<<<BB, 512, 0, stream>>>(
        q, heads, tails, rels, ent, rel, w1, b1, w2, b2, out);
}

// Round 3
// 72.866 us; speedup vs baseline: 1.5804x; 1.5804x over previous
//
#include <hip/hip_runtime.h>

// Problem constants (fixed by the reference)
#define BB 2048
#define CC 50
#define DD 512
#define HH 51   // D // 10

__global__ __launch_bounds__(512) void ConstraintFuser_kernel(
    const float* __restrict__ q,      // [B, D]
    const int*   __restrict__ heads,  // [B, C]
    const int*   __restrict__ tails,  // [B, C]
    const int*   __restrict__ rels,   // [B, C]
    const float* __restrict__ ent,    // [NE+1, D]
    const float* __restrict__ rel,    // [NR+1, D]
    const float* __restrict__ w1,     // [D, H]
    const float* __restrict__ b1,     // [H]
    const float* __restrict__ w2,     // [H, D]
    const float* __restrict__ b2,     // [D]
    float* __restrict__ out)          // [B, D]
{
    const int b    = blockIdx.x;
    const int tid  = threadIdx.x;
    const int wave = tid >> 6;
    const int lane = tid & 63;

    __shared__ float  s_q[DD];           // 2 KB
    __shared__ float4 s_pp[8][128];      // 16 KB — per-wave pooled partials; reused as 4x128 reduce buf
    __shared__ float  s_pool[DD];        // 2 KB
    __shared__ float  s_wred[8][HH];
    __shared__ float  s_mid[HH];
    __shared__ int    s_h[CC], s_t[CC], s_r[CC];

    // ---- stage indices + query row ----
    if (tid < CC) {
        s_h[tid] = heads[b * CC + tid];
        s_t[tid] = tails[b * CC + tid];
        s_r[tid] = rels [b * CC + tid];
    }
    if (tid < 128) {
        ((float4*)s_q)[tid] = ((const float4*)(q + (size_t)b * DD))[tid];
    }
    __syncthreads();

    // each lane's fixed 8-float slot of q
    const float4 q0 = ((const float4*)s_q)[lane * 2];
    const float4 q1 = ((const float4*)s_q)[lane * 2 + 1];

    // ---- merged phase 1+2: barrier-free per-wave score + pool stream ----
    // wave w handles c = w, w+8, ... ; score broadcast via butterfly shfl;
    // t/r loads are independent of the score chain -> stay in flight.
    float4 acc0 = make_float4(0.f, 0.f, 0.f, 0.f);
    float4 acc1 = make_float4(0.f, 0.f, 0.f, 0.f);
    #pragma unroll 2
    for (int c = wave; c < CC; c += 8) {
        const float4* hrow = (const float4*)(ent + (size_t)s_h[c] * DD);
        const float4* trow = (const float4*)(ent + (size_t)s_t[c] * DD);
        const float4* rrow = (const float4*)(rel + (size_t)s_r[c] * DD);
        const float4 h0 = hrow[lane * 2];
        const float4 h1 = hrow[lane * 2 + 1];
        const float4 t0 = trow[lane * 2];
        const float4 t1 = trow[lane * 2 + 1];
        const float4 r0 = rrow[lane * 2];
        const float4 r1 = rrow[lane * 2 + 1];
        float p = q0.x * h0.x + q0.y * h0.y + q0.z * h0.z + q0.w * h0.w
                + q1.x * h1.x + q1.y * h1.y + q1.z * h1.z + q1.w * h1.w;
        #pragma unroll
        for (int off = 32; off > 0; off >>= 1) p += __shfl_xor(p, off, 64);
        acc0.x += p * (t0.x + r0.x);
        acc0.y += p * (t0.y + r0.y);
        acc0.z += p * (t0.z + r0.z);
        acc0.w += p * (t0.w + r0.w);
        acc1.x += p * (t1.x + r1.x);
        acc1.y += p * (t1.y + r1.y);
        acc1.z += p * (t1.z + r1.z);
        acc1.w += p * (t1.w + r1.w);
    }
    s_pp[wave][lane * 2]     = acc0;   // s_pp[w][j] = float4 j of wave-w partial pooled
    s_pp[wave][lane * 2 + 1] = acc1;
    __syncthreads();

    // ---- reduce 8 per-wave partials -> s_pool ----
    if (tid < 128) {
        float4 s = s_pp[0][tid];
        #pragma unroll
        for (int w = 1; w < 8; ++w) {
            const float4 a = s_pp[w][tid];
            s.x += a.x; s.y += a.y; s.z += a.z; s.w += a.w;
        }
        ((float4*)s_pool)[tid] = s;
    }
    __syncthreads();

    // ---- phase 3: mid = relu(pooled @ w1 + b1); wave w owns d in [64w, 64w+64) ----
    if (lane < HH) {
        const int d0 = wave * 64;
        float partial = 0.f;
        #pragma unroll 8
        for (int j = 0; j < 64; ++j) {
            partial += s_pool[d0 + j] * w1[(size_t)(d0 + j) * HH + lane];
        }
        s_wred[wave][lane] = partial;
    }
    __syncthreads();
    if (tid < HH) {
        float m = b1[tid];
        #pragma unroll
        for (int w = 0; w < 8; ++w) m += s_wred[w][tid];
        s_mid[tid] = m > 0.f ? m : 0.f;
    }
    __syncthreads();

    // ---- phase 4: out = mid @ w2 + b2 + q ----
    const int cg = tid >> 7;    // 0..3
    const int dv = tid & 127;   // float4 index within row
    float4 acc2 = make_float4(0.f, 0.f, 0.f, 0.f);
    #pragma unroll
    for (int i = 0; i < 13; ++i) {
        const int h = cg + i * 4;
        if (h < HH) {
            const float  m  = s_mid[h];
            const float4 wv = ((const float4*)(w2 + (size_t)h * DD))[dv];
            acc2.x += m * wv.x;
            acc2.y += m * wv.y;
            acc2.z += m * wv.z;
            acc2.w += m * wv.w;
        }
    }
    float4 (*s_red4)[128] = (float4 (*)[128])s_pp;   // reuse the 16 KB buffer
    s_red4[cg][dv] = acc2;
    __syncthreads();
    if (tid < 128) {
        const float4 a0 = s_red4[0][tid];
        const float4 a1 = s_red4[1][tid];
        const float4 a2 = s_red4[2][tid];
        const float4 a3 = s_red4[3][tid];
        const float4 bb = ((const float4*)b2)[tid];
        const float4 qq = ((const float4*)s_q)[tid];
        float4 o;
        o.x = a0.x + a1.x + a2.x + a3.x + bb.x + qq.x;
        o.y = a0.y + a1.y + a2.y + a3.y + bb.y + qq.y;
        o.z = a0.z + a1.z + a2.z + a3.z + bb.z + qq.z;
        o.w = a0.w + a1.w + a2.w + a3.w + bb.w + qq.w;
        ((float4*)(out + (size_t)b * DD))[tid] = o;
    }
}

extern "C" void kernel_launch(void* const* d_in, const int* in_sizes, int n_in,
                              void* d_out, int out_size, void* d_ws, size_t ws_size,
                              hipStream_t stream) {
    const float* q     = (const float*)d_in[0];
    const int*   heads = (const int*)  d_in[1];
    const int*   tails = (const int*)  d_in[2];
    const int*   rels  = (const int*)  d_in[3];
    const float* ent   = (const float*)d_in[4];
    const float* rel   = (const float*)d_in[5];
    const float* w1    = (const float*)d_in[6];
    const float* b1    = (const float*)d_in[7];
    const float* w2    = (const float*)d_in[8];
    const float* b2    = (const float*)d_in[9];
    float* out = (float*)d_out;

    ConstraintFuser_kernel<<<BB, 512, 0, stream>>>(
        q, heads, tails, rels, ent, rel, w1, b1, w2, b2, out);
}